// Round 15
// baseline (4215.673 us; speedup 1.0000x reference)
//
#include <hip/hip_runtime.h>
#include <math.h>

#define BATCH 64
#define NREF  256
#define NPTS  2048
#define DIM   128
#define ITERS 100
// Base-2 logit domain: C2 = (C/eps)*log2e; u2,v2 likewise scaled (r13: -305us).
#define C2SCALE 1442.6950408889634f   // INV_EPS * log2(e)
#define RPW    8                 // rows per wave in uv
#define NCHUNK 32                // NREF / RPW

#if __has_builtin(__builtin_amdgcn_exp2f)
__device__ __forceinline__ float fexp2(float x) { return __builtin_amdgcn_exp2f(x); }
#else
__device__ __forceinline__ float fexp2(float x) { return exp2f(x); }
#endif
#if __has_builtin(__builtin_amdgcn_logf)
__device__ __forceinline__ float flog2(float x) { return __builtin_amdgcn_logf(x); }
#else
__device__ __forceinline__ float flog2(float x) { return log2f(x); }
#endif

// Branchless single-exp online LSE step, base-2 (round-0 idiom).
// m=-inf start: e=2^(-inf)=0 -> s=1 on first step.
__device__ __forceinline__ void lse_step2(float t, float& m, float& s) {
    float nm = fmaxf(m, t);
    float e  = fexp2(m + t - 2.0f * nm);       // 2^(-|m-t|)
    float s1 = fmaf(s, e, 1.0f);               // t is new max
    float s2 = s + e;                          // t <= m
    s = (t > m) ? s1 : s2;
    m = nm;
}

// __launch_bounds__ (measured r5/r7/r8): 2nd arg = min BLOCKS per CU (CUDA
// semantics). Spill shows as GBs of phantom FETCH/WRITE (r7).
//
// Loop history: VALU/trans-bound (r10-r13); barriers force vmcnt-drain stalls
// (r11 diag; r12 counted-barrier attempt REGRESSED); head-fusion of vmerge
// REGRESSED (r14: 16x redundancy). r15: wave-owns-row uv -- zero barriers,
// in-wave butterfly reduce only, branchless 1-exp column merge.

// ---------- C2 via GEMM tiling + inline row norms ----------
__global__ __launch_bounds__(256) void cgemm_kernel(const float* __restrict__ X,
                                                    const float* __restrict__ ref,
                                                    float* __restrict__ C) {
    __shared__ float rs[8 * 128];
    __shared__ float xs[8 * 128];
    __shared__ float r2s[128];
    __shared__ float x2s[128];
    int b  = blockIdx.x >> 5;
    int it = (blockIdx.x >> 4) & 1;
    int jt = blockIdx.x & 15;
    int i0 = it * 128, j0 = jt * 128;
    int t  = threadIdx.x;
    int ti = t >> 4, tj = t & 15;

    int sr = t >> 1;                     // staging row 0..127
    int sh = (t & 1) * 4;                // k-offset 0 or 4
    const float* refp = ref + (size_t)(i0 + sr) * DIM + sh;
    const float* xp   = X + ((size_t)b * NPTS + j0 + sr) * DIM + sh;

    float4 acc[2][2][4];
#pragma unroll
    for (int p = 0; p < 2; ++p)
#pragma unroll
        for (int q = 0; q < 2; ++q)
#pragma unroll
            for (int ii = 0; ii < 4; ++ii)
                acc[p][q][ii] = make_float4(0.f, 0.f, 0.f, 0.f);
    float rsq = 0.f, xsq = 0.f;

    for (int k0 = 0; k0 < DIM; k0 += 8) {
        float4 rv = *(const float4*)(refp + k0);
        float4 xv = *(const float4*)(xp + k0);
        rsq += rv.x * rv.x + rv.y * rv.y + rv.z * rv.z + rv.w * rv.w;
        xsq += xv.x * xv.x + xv.y * xv.y + xv.z * xv.z + xv.w * xv.w;
        __syncthreads();                 // previous compute done before overwrite
        rs[(sh + 0) * 128 + sr] = rv.x; rs[(sh + 1) * 128 + sr] = rv.y;
        rs[(sh + 2) * 128 + sr] = rv.z; rs[(sh + 3) * 128 + sr] = rv.w;
        xs[(sh + 0) * 128 + sr] = xv.x; xs[(sh + 1) * 128 + sr] = xv.y;
        xs[(sh + 2) * 128 + sr] = xv.z; xs[(sh + 3) * 128 + sr] = xv.w;
        __syncthreads();

        const float4* rs4 = (const float4*)rs;
        const float4* xs4 = (const float4*)xs;
#pragma unroll
        for (int k = 0; k < 8; ++k) {
            float4 a0 = rs4[k * 32 + ti];
            float4 a1 = rs4[k * 32 + 16 + ti];
            float4 b0 = xs4[k * 32 + tj];
            float4 b1 = xs4[k * 32 + 16 + tj];
#define FMA4(ACC, S, BV)                                                     \
            ACC.x = fmaf(S, BV.x, ACC.x); ACC.y = fmaf(S, BV.y, ACC.y);      \
            ACC.z = fmaf(S, BV.z, ACC.z); ACC.w = fmaf(S, BV.w, ACC.w);
#define ROW(P, S, II)                                                        \
            FMA4(acc[P][0][II], S, b0) FMA4(acc[P][1][II], S, b1)
            ROW(0, a0.x, 0) ROW(0, a0.y, 1) ROW(0, a0.z, 2) ROW(0, a0.w, 3)
            ROW(1, a1.x, 0) ROW(1, a1.y, 1) ROW(1, a1.z, 2) ROW(1, a1.w, 3)
#undef ROW
#undef FMA4
        }
    }

    rsq += __shfl_xor(rsq, 1);           // combine the two k-halves of row sr
    xsq += __shfl_xor(xsq, 1);
    if ((t & 1) == 0) { r2s[sr] = rsq; x2s[sr] = xsq; }
    __syncthreads();

    float x2v[2][4];
#pragma unroll
    for (int q = 0; q < 2; ++q)
#pragma unroll
        for (int e = 0; e < 4; ++e)
            x2v[q][e] = x2s[q * 64 + tj * 4 + e];

#pragma unroll
    for (int p = 0; p < 2; ++p)
#pragma unroll
        for (int ii = 0; ii < 4; ++ii) {
            int il = p * 64 + ti * 4 + ii;
            float rr = r2s[il];
            float* crow = C + ((size_t)b * NREF + i0 + il) * NPTS + j0;
#pragma unroll
            for (int q = 0; q < 2; ++q) {
                float4 av = acc[p][q][ii];
                float4 o;
                o.x = sqrtf(fmaxf(rr + x2v[q][0] - 2.f * av.x, 0.f)) * C2SCALE;
                o.y = sqrtf(fmaxf(rr + x2v[q][1] - 2.f * av.y, 0.f)) * C2SCALE;
                o.z = sqrtf(fmaxf(rr + x2v[q][2] - 2.f * av.z, 0.f)) * C2SCALE;
                o.w = sqrtf(fmaxf(rr + x2v[q][3] - 2.f * av.w, 0.f)) * C2SCALE;
                *(float4*)(crow + q * 64 + tj * 4) = o;
            }
        }
}

// ---------- fused u+column-partial: WAVE-OWNS-ROW, zero barriers ----------
// Wave = (batch, 8-row chunk); lane holds 32 columns (cols k*256+4*lane+e,
// k=0..7) of the current row. Row LSE: in-wave 6-step butterfly (no LDS, no
// __syncthreads -> loads pipeline across rows, no vmcnt drain). Column merge:
// branchless 1-exp lse_step2 into pm/ps[8] (64 VGPR). ~115 VGPR live;
// (256,2) caps at 256 -> no spill. 2048 waves = 8/CU.
__global__ __launch_bounds__(256, 2) void uv_kernel(const float* __restrict__ C,
                                                    const float* __restrict__ v,
                                                    float* __restrict__ u,
                                                    float* __restrict__ Pl,
                                                    float log_wx) {
    int lane  = threadIdx.x & 63;
    int gw    = blockIdx.x * 4 + (threadIdx.x >> 6);
    int b     = gw >> 5;                 // 32 chunks per batch
    int chunk = gw & 31;
    const float* Cb = C + (size_t)(b * NREF + chunk * RPW) * NPTS;
    const float* vb = v + (size_t)b * NPTS;
    int c0 = 4 * lane;                   // column offset within each 256-group

    float4 pm[8], ps[8];
#pragma unroll
    for (int k = 0; k < 8; ++k) {
        pm[k] = make_float4(-INFINITY, -INFINITY, -INFINITY, -INFINITY);
        ps[k] = make_float4(0.f, 0.f, 0.f, 0.f);
    }

#pragma unroll 2
    for (int r = 0; r < RPW; ++r) {
        const float* row = Cb + (size_t)r * NPTS;
        float4 a[8];
#pragma unroll
        for (int k = 0; k < 8; ++k) {
            float4 cv = *(const float4*)(row + k * 256 + c0);
            float4 vv = *(const float4*)(vb + k * 256 + c0);
            a[k].x = vv.x - cv.x; a[k].y = vv.y - cv.y;
            a[k].z = vv.z - cv.z; a[k].w = vv.w - cv.w;
        }
        // row max: lane-local chain, then 6-step butterfly
        float m = fmaxf(fmaxf(a[0].x, a[0].y), fmaxf(a[0].z, a[0].w));
#pragma unroll
        for (int k = 1; k < 8; ++k)
            m = fmaxf(m, fmaxf(fmaxf(a[k].x, a[k].y), fmaxf(a[k].z, a[k].w)));
#pragma unroll
        for (int off = 1; off < 64; off <<= 1)
            m = fmaxf(m, __shfl_xor(m, off));
        // row sum (exact shift)
        float s = 0.f;
#pragma unroll
        for (int k = 0; k < 8; ++k)
            s += fexp2(a[k].x - m) + fexp2(a[k].y - m)
               + fexp2(a[k].z - m) + fexp2(a[k].w - m);
#pragma unroll
        for (int off = 1; off < 64; off <<= 1)
            s += __shfl_xor(s, off);
        float su = log_wx - (m + flog2(s));     // u2_new for this row
        if (lane == 0) u[b * NREF + chunk * RPW + r] = su;

        // column merge: t = (v2 - C2) + u2; per-column online LSE (1 exp/elem)
#pragma unroll
        for (int k = 0; k < 8; ++k) {
            lse_step2(a[k].x + su, pm[k].x, ps[k].x);
            lse_step2(a[k].y + su, pm[k].y, ps[k].y);
            lse_step2(a[k].z + su, pm[k].z, ps[k].z);
            lse_step2(a[k].w + su, pm[k].w, ps[k].w);
        }
    }

    // Pl = (pm - v_j) + log2(ps)  (chunk-partial column logit, v_j removed)
    float* plb = Pl + (size_t)(b * NCHUNK + chunk) * NPTS;
#pragma unroll
    for (int k = 0; k < 8; ++k) {
        float4 vv = *(const float4*)(vb + k * 256 + c0);
        float4 pl;
        pl.x = (pm[k].x - vv.x) + flog2(ps[k].x);
        pl.y = (pm[k].y - vv.y) + flog2(ps[k].y);
        pl.z = (pm[k].z - vv.z) + flog2(ps[k].z);
        pl.w = (pm[k].w - vv.w) + flog2(ps[k].w);
        *(float4*)(plb + k * 256 + c0) = pl;
    }
}

// ---------- merge 32 chunk logits per column -> v ----------
__global__ __launch_bounds__(256) void vmerge_kernel(const float* __restrict__ Pl,
                                                     float* __restrict__ v,
                                                     float log_wy) {
    int b = blockIdx.x >> 3;
    int j = ((blockIdx.x & 7) << 8) + threadIdx.x;
    const float* p = Pl + (size_t)b * NCHUNK * NPTS + j;
    float l[NCHUNK];
#pragma unroll
    for (int c = 0; c < NCHUNK; ++c) l[c] = p[(size_t)c * NPTS];
    float m = l[0];
#pragma unroll
    for (int c = 1; c < NCHUNK; ++c) m = fmaxf(m, l[c]);
    float s = 0.f;
#pragma unroll
    for (int c = 0; c < NCHUNK; ++c) s += fexp2(l[c] - m);
    v[(size_t)b * NPTS + j] = log_wy - (m + flog2(s));
}

// ---------- epilogue Path A phase 1: j-split 8, 16-col inner tile ----------
// JT=16: 88 VGPR measured (r9), no spill (WRITE=66MB logical). Swizzle: 4
// quads/row, store q^((r>>3)&3), read q^(g&3). w = 2^(u2+v2-C2).
__global__ __launch_bounds__(512, 2) void out_partialA(const float* __restrict__ C,
                                                       const float* __restrict__ X,
                                                       const float* __restrict__ u,
                                                       const float* __restrict__ v,
                                                       float* __restrict__ Np,
                                                       float* __restrict__ denp) {
    __shared__ float wts[NREF * 16];    // [r][4 float4, swizzled]  16 KB
    __shared__ float xt[16 * DIM];      // [jj][d]                   8 KB
    int b  = blockIdx.x >> 3;
    int jc = blockIdx.x & 7;
    int j0 = jc * 256;
    int t  = threadIdx.x;
    int s  = t & 15;                    // d-slot
    int g  = t >> 4;                    // row group: rows g*8 .. g*8+7

    const float* Cb = C + (size_t)b * NREF * NPTS + j0;
    const float* ub = u + b * NREF;
    const float* vb = v + (size_t)b * NPTS + j0;

    float4 a0[8], a1[8];
    float ws[8];
#pragma unroll
    for (int r = 0; r < 8; ++r) {
        a0[r] = make_float4(0.f, 0.f, 0.f, 0.f);
        a1[r] = make_float4(0.f, 0.f, 0.f, 0.f);
        ws[r] = 0.f;
    }

    for (int jt = 0; jt < 256; jt += 16) {
        // stage wt: 256 rows x 16 cols = 1024 float4, 2 per thread
#pragma unroll
        for (int k = 0; k < 2; ++k) {
            int fidx = t + 512 * k;
            int r = fidx >> 2, q = fidx & 3;
            float4 cv = *(const float4*)(Cb + (size_t)r * NPTS + jt + 4 * q);
            float4 vv = *(const float4*)(vb + jt + 4 * q);
            float uu = ub[r];
            float4 wv;
            wv.x = fexp2(uu + vv.x - cv.x);
            wv.y = fexp2(uu + vv.y - cv.y);
            wv.z = fexp2(uu + vv.z - cv.z);
            wv.w = fexp2(uu + vv.w - cv.w);
            int sw = q ^ ((r >> 3) & 3);
            *(float4*)&wts[r * 16 + sw * 4] = wv;
        }
        // stage X-tile: 16 rows x 128 d = 512 float4, 1 per thread (contiguous 8KB)
        const float4* Xb4 = (const float4*)(X + ((size_t)b * NPTS + j0 + jt) * DIM);
        ((float4*)xt)[t] = Xb4[t];
        __syncthreads();

        const float4* xt4 = (const float4*)xt;
#pragma unroll 2
        for (int jp = 0; jp < 8; ++jp) {        // jj = 2*jp, 2*jp+1
            int j1 = 2 * jp;
            float4 xa0 = xt4[j1 * 32 + s];
            float4 xa1 = xt4[j1 * 32 + 16 + s];
            float4 xb0 = xt4[(j1 + 1) * 32 + s];
            float4 xb1 = xt4[(j1 + 1) * 32 + 16 + s];
            int q   = jp >> 1;
            int h   = jp & 1;
            int swb = (q ^ (g & 3)) * 4 + 2 * h;   // float offset within row's 16
#pragma unroll
            for (int rr = 0; rr < 8; ++rr) {
                int r = g * 8 + rr;
                float2 w2 = *(const float2*)&wts[r * 16 + swb];
                a0[rr].x = fmaf(w2.x, xa0.x, a0[rr].x);
                a0[rr].y = fmaf(w2.x, xa0.y, a0[rr].y);
                a0[rr].z = fmaf(w2.x, xa0.z, a0[rr].z);
                a0[rr].w = fmaf(w2.x, xa0.w, a0[rr].w);
                a1[rr].x = fmaf(w2.x, xa1.x, a1[rr].x);
                a1[rr].y = fmaf(w2.x, xa1.y, a1[rr].y);
                a1[rr].z = fmaf(w2.x, xa1.z, a1[rr].z);
                a1[rr].w = fmaf(w2.x, xa1.w, a1[rr].w);
                a0[rr].x = fmaf(w2.y, xb0.x, a0[rr].x);
                a0[rr].y = fmaf(w2.y, xb0.y, a0[rr].y);
                a0[rr].z = fmaf(w2.y, xb0.z, a0[rr].z);
                a0[rr].w = fmaf(w2.y, xb0.w, a0[rr].w);
                a1[rr].x = fmaf(w2.y, xb1.x, a1[rr].x);
                a1[rr].y = fmaf(w2.y, xb1.y, a1[rr].y);
                a1[rr].z = fmaf(w2.y, xb1.z, a1[rr].z);
                a1[rr].w = fmaf(w2.y, xb1.w, a1[rr].w);
                ws[rr] += w2.x + w2.y;
            }
        }
        __syncthreads();
    }

    // plain coalesced stores of this block's partials (disjoint (b,jc) planes)
    float* npb = Np + ((size_t)jc * BATCH * NREF + (size_t)b * NREF) * DIM;
#pragma unroll
    for (int rr = 0; rr < 8; ++rr) {
        int r = g * 8 + rr;
        float4* nrow = (float4*)(npb + (size_t)r * DIM);
        nrow[s]      = a0[rr];
        nrow[16 + s] = a1[rr];
        if (s == 0) denp[(size_t)jc * BATCH * NREF + b * NREF + r] = ws[rr];
    }
}

// ---------- epilogue Path A phase 2: deterministic 8-way combine ----------
__global__ __launch_bounds__(256) void out_finishA(const float* __restrict__ Np,
                                                   const float* __restrict__ denp,
                                                   const float* __restrict__ ref,
                                                   float* __restrict__ out) {
    const int NPL  = BATCH * NREF * DIM / 4;        // float4 per plane
    const int DENP = BATCH * NREF;
    int fidx = blockIdx.x * 256 + threadIdx.x;      // float4 index, 524288 total
    int bi   = fidx >> 5;                           // b*256 + i
    float4 n4 = make_float4(0.f, 0.f, 0.f, 0.f);
    float dn = 0.f;
    const float4* np4 = (const float4*)Np;
#pragma unroll
    for (int jc = 0; jc < 8; ++jc) {                // fixed ascending order
        float4 p = np4[(size_t)jc * NPL + fidx];
        n4.x += p.x; n4.y += p.y; n4.z += p.z; n4.w += p.w;
        dn += denp[(size_t)jc * DENP + bi];
    }
    float inv = 1.0f / (dn + 1e-8f);
    int i = bi & 255;                               // row within batch
    int q = fidx & 31;                              // d-quad
    float4 rf = ((const float4*)ref)[i * 32 + q];
    float4 o;
    o.x = n4.x * inv - rf.x;
    o.y = n4.y * inv - rf.y;
    o.z = n4.z * inv - rf.z;
    o.w = n4.w * inv - rf.w;
    ((float4*)out)[fidx] = o;
}

// ---------- epilogue Path B (fallback, proven round-3): i-split 32-row blocks ----------
__global__ __launch_bounds__(256) void out_kernelB(const float* __restrict__ C,
                                                   const float* __restrict__ X,
                                                   const float* __restrict__ ref,
                                                   const float* __restrict__ u,
                                                   const float* __restrict__ v,
                                                   float* __restrict__ out) {
    __shared__ float wt[32 * 32];       // [row_local][jj]  4 KB
    __shared__ float xt[32 * DIM];      // [jj][d]         16 KB
    int b  = blockIdx.x >> 3;
    int it = blockIdx.x & 7;
    int i0 = it * 32;
    int t  = threadIdx.x;
    int s  = t & 31;                    // d-slot (float4 at d = 4s)
    int g  = t >> 5;                    // rows i0 + g*4 .. +3

    const float* Cb = C + ((size_t)b * NREF + i0) * NPTS;
    const float* vb = v + (size_t)b * NPTS;
    const float* ub = u + (size_t)b * NREF + i0;

    float4 acc[4];
    float wsum[4];
#pragma unroll
    for (int r = 0; r < 4; ++r) { acc[r] = make_float4(0.f, 0.f, 0.f, 0.f); wsum[r] = 0.f; }

    for (int j0 = 0; j0 < NPTS; j0 += 32) {
#pragma unroll
        for (int k = 0; k < 4; ++k) {
            int widx = t + 256 * k;
            int r    = widx >> 5;
            int jj   = widx & 31;
            wt[widx] = fexp2(ub[r] + vb[j0 + jj] - Cb[(size_t)r * NPTS + j0 + jj]);
        }
        const float4* Xb4 = (const float4*)(X + ((size_t)b * NPTS + j0) * DIM);
#pragma unroll
        for (int k = 0; k < 4; ++k) {
            int idx = t + 256 * k;
            ((float4*)xt)[idx] = Xb4[idx];
        }
        __syncthreads();

        const float4* xt4 = (const float4*)xt;
#pragma unroll 2
        for (int jj = 0; jj < 32; jj += 4) {
            float4 xv0 = xt4[(jj + 0) * 32 + s];
            float4 xv1 = xt4[(jj + 1) * 32 + s];
            float4 xv2 = xt4[(jj + 2) * 32 + s];
            float4 xv3 = xt4[(jj + 3) * 32 + s];
#pragma unroll
            for (int r = 0; r < 4; ++r) {
                float4 w4 = *(const float4*)&wt[(g * 4 + r) * 32 + jj];
                acc[r].x = fmaf(w4.x, xv0.x, acc[r].x); acc[r].y = fmaf(w4.x, xv0.y, acc[r].y);
                acc[r].z = fmaf(w4.x, xv0.z, acc[r].z); acc[r].w = fmaf(w4.x, xv0.w, acc[r].w);
                acc[r].x = fmaf(w4.y, xv1.x, acc[r].x); acc[r].y = fmaf(w4.y, xv1.y, acc[r].y);
                acc[r].z = fmaf(w4.y, xv1.z, acc[r].z); acc[r].w = fmaf(w4.y, xv1.w, acc[r].w);
                acc[r].x = fmaf(w4.z, xv2.x, acc[r].x); acc[r].y = fmaf(w4.z, xv2.y, acc[r].y);
                acc[r].z = fmaf(w4.z, xv2.z, acc[r].z); acc[r].w = fmaf(w4.z, xv2.w, acc[r].w);
                acc[r].x = fmaf(w4.w, xv3.x, acc[r].x); acc[r].y = fmaf(w4.w, xv3.y, acc[r].y);
                acc[r].z = fmaf(w4.w, xv3.z, acc[r].z); acc[r].w = fmaf(w4.w, xv3.w, acc[r].w);
                wsum[r] += (w4.x + w4.y) + (w4.z + w4.w);
            }
        }
        __syncthreads();
    }

#pragma unroll
    for (int r = 0; r < 4; ++r) {
        int i = i0 + g * 4 + r;
        float dn = wsum[r] + 1e-8f;
        float inv = 1.0f / dn;
        float4 rf = ((const float4*)(ref + (size_t)i * DIM))[s];
        float4 o;
        o.x = acc[r].x * inv - rf.x;
        o.y = acc[r].y * inv - rf.y;
        o.z = acc[r].z * inv - rf.z;
        o.w = acc[r].w * inv - rf.w;
        ((float4*)(out + ((size_t)b * NREF + i) * DIM))[s] = o;
    }
}

extern "C" void kernel_launch(void* const* d_in, const int* in_sizes, int n_in,
                              void* d_out, int out_size, void* d_ws, size_t ws_size,
                              hipStream_t stream) {
    const float* X   = (const float*)d_in[0];
    const float* ref = (const float*)d_in[1];
    float* out = (float*)d_out;

    char* ws = (char*)d_ws;
    size_t o = 0;
    float* C = (float*)(ws + o); o += (size_t)BATCH * NREF * NPTS * sizeof(float);
    float* u = (float*)(ws + o); o += (size_t)BATCH * NREF * sizeof(float);
    float* v = (float*)(ws + o); o += (size_t)BATCH * NPTS * sizeof(float);
    // Pl (loop partials, 16.8 MB) is dead after the final vmerge; Np (67.1 MB)
    // aliases it (out_partialA runs after vmerge has extracted v).
    float* Pl = (float*)(ws + o);
    float* Np = (float*)(ws + o);
    size_t oA = o + (size_t)8 * BATCH * NREF * DIM * sizeof(float);
    float* denp = (float*)(ws + oA);
    oA += (size_t)8 * BATCH * NREF * sizeof(float);
    bool bigws = (ws_size >= oA);       // Path A needs ~202.4 MB total

    // base-2 logit constants: lw2 = ln(w + 1e-8) * log2(e)
    const float log_wx = (float)(log(1.0 / (double)NREF + 1e-8) * 1.4426950408889634);
    const float log_wy = (float)(log(1.0 / (double)NPTS + 1e-8) * 1.4426950408889634);

    hipMemsetAsync(v, 0, (size_t)BATCH * NPTS * sizeof(float), stream);

    cgemm_kernel<<<BATCH * 32, 256, 0, stream>>>(X, ref, C);

    for (int t = 0; t < ITERS; ++t) {
        uv_kernel<<<BATCH * NCHUNK / 4, 256, 0, stream>>>(C, v, u, Pl, log_wx);
        vmerge_kernel<<<BATCH * NPTS / 256, 256, 0, stream>>>(Pl, v, log_wy);
    }

    if (bigws) {
        out_partialA<<<BATCH * 8, 512, 0, stream>>>(C, X, u, v, Np, denp);
        out_finishA<<<BATCH * NREF * DIM / 1024, 256, 0, stream>>>(Np, denp, ref, out);
    } else {
        out_kernelB<<<BATCH * 8, 256, 0, stream>>>(C, X, ref, u, v, out);
    }
}

// Round 16
// 3624.252 us; speedup vs baseline: 1.1632x; 1.1632x over previous
//
#include <hip/hip_runtime.h>
#include <math.h>

#define BATCH 64
#define NREF  256
#define NPTS  2048
#define DIM   128
#define ITERS 100
// Base-2 logit domain: C2 = (C/eps)*log2e; u2,v2 likewise scaled. All exp/log
// are raw v_exp_f32/v_log_f32 (2^x / log2 x) -- saves the ln2-scale mul on
// every transcendental (r13: -305us, matched prediction).
#define C2SCALE 1442.6950408889634f   // INV_EPS * log2(e)
#define RCH    4                 // rows per register tile in uv
#define NSUB   4                 // sequential sub-chunks per uv block
#define NCHUNK 16                // output chunks (16 rows each): NREF/(RCH*NSUB)

#if __has_builtin(__builtin_amdgcn_exp2f)
__device__ __forceinline__ float fexp2(float x) { return __builtin_amdgcn_exp2f(x); }
#else
__device__ __forceinline__ float fexp2(float x) { return exp2f(x); }
#endif
#if __has_builtin(__builtin_amdgcn_logf)
__device__ __forceinline__ float flog2(float x) { return __builtin_amdgcn_logf(x); }
#else
__device__ __forceinline__ float flog2(float x) { return log2f(x); }
#endif

// __launch_bounds__ (measured r5/r7/r8): 2nd arg = min BLOCKS per CU (CUDA
// semantics). (512,4)->64-VGPR cap; (512,3)->85; (512,2)->128. Spill shows as
// GBs of phantom FETCH/WRITE (r7: 4.8GB WRITE on a 67MB-logical kernel).
//
// Loop model (validated r10-r15): VALU/trans-bound. Refuted levers: occupancy
// 16/24/32 waves (r10/r11 flat), counted-barrier pipelining (r12: +5.6us/iter),
// vmerge head-fusion (r14: 16x redundancy, +5.5), wave-owns-row + 1-exp merge
// (r15: serial dep chain + more ops, +5.8). r13's structure is the floor:
// trans ~15us/iter + VALU issue ~18us/iter overlapped, mem 22us hidden.

// ---------- C2 via GEMM tiling + inline row norms ----------
__global__ __launch_bounds__(256) void cgemm_kernel(const float* __restrict__ X,
                                                    const float* __restrict__ ref,
                                                    float* __restrict__ C) {
    __shared__ float rs[8 * 128];
    __shared__ float xs[8 * 128];
    __shared__ float r2s[128];
    __shared__ float x2s[128];
    int b  = blockIdx.x >> 5;
    int it = (blockIdx.x >> 4) & 1;
    int jt = blockIdx.x & 15;
    int i0 = it * 128, j0 = jt * 128;
    int t  = threadIdx.x;
    int ti = t >> 4, tj = t & 15;

    int sr = t >> 1;                     // staging row 0..127
    int sh = (t & 1) * 4;                // k-offset 0 or 4
    const float* refp = ref + (size_t)(i0 + sr) * DIM + sh;
    const float* xp   = X + ((size_t)b * NPTS + j0 + sr) * DIM + sh;

    float4 acc[2][2][4];
#pragma unroll
    for (int p = 0; p < 2; ++p)
#pragma unroll
        for (int q = 0; q < 2; ++q)
#pragma unroll
            for (int ii = 0; ii < 4; ++ii)
                acc[p][q][ii] = make_float4(0.f, 0.f, 0.f, 0.f);
    float rsq = 0.f, xsq = 0.f;

    for (int k0 = 0; k0 < DIM; k0 += 8) {
        float4 rv = *(const float4*)(refp + k0);
        float4 xv = *(const float4*)(xp + k0);
        rsq += rv.x * rv.x + rv.y * rv.y + rv.z * rv.z + rv.w * rv.w;
        xsq += xv.x * xv.x + xv.y * xv.y + xv.z * xv.z + xv.w * xv.w;
        __syncthreads();                 // previous compute done before overwrite
        rs[(sh + 0) * 128 + sr] = rv.x; rs[(sh + 1) * 128 + sr] = rv.y;
        rs[(sh + 2) * 128 + sr] = rv.z; rs[(sh + 3) * 128 + sr] = rv.w;
        xs[(sh + 0) * 128 + sr] = xv.x; xs[(sh + 1) * 128 + sr] = xv.y;
        xs[(sh + 2) * 128 + sr] = xv.z; xs[(sh + 3) * 128 + sr] = xv.w;
        __syncthreads();

        const float4* rs4 = (const float4*)rs;
        const float4* xs4 = (const float4*)xs;
#pragma unroll
        for (int k = 0; k < 8; ++k) {
            float4 a0 = rs4[k * 32 + ti];
            float4 a1 = rs4[k * 32 + 16 + ti];
            float4 b0 = xs4[k * 32 + tj];
            float4 b1 = xs4[k * 32 + 16 + tj];
#define FMA4(ACC, S, BV)                                                     \
            ACC.x = fmaf(S, BV.x, ACC.x); ACC.y = fmaf(S, BV.y, ACC.y);      \
            ACC.z = fmaf(S, BV.z, ACC.z); ACC.w = fmaf(S, BV.w, ACC.w);
#define ROW(P, S, II)                                                        \
            FMA4(acc[P][0][II], S, b0) FMA4(acc[P][1][II], S, b1)
            ROW(0, a0.x, 0) ROW(0, a0.y, 1) ROW(0, a0.z, 2) ROW(0, a0.w, 3)
            ROW(1, a1.x, 0) ROW(1, a1.y, 1) ROW(1, a1.z, 2) ROW(1, a1.w, 3)
#undef ROW
#undef FMA4
        }
    }

    rsq += __shfl_xor(rsq, 1);           // combine the two k-halves of row sr
    xsq += __shfl_xor(xsq, 1);
    if ((t & 1) == 0) { r2s[sr] = rsq; x2s[sr] = xsq; }
    __syncthreads();

    float x2v[2][4];
#pragma unroll
    for (int q = 0; q < 2; ++q)
#pragma unroll
        for (int e = 0; e < 4; ++e)
            x2v[q][e] = x2s[q * 64 + tj * 4 + e];

#pragma unroll
    for (int p = 0; p < 2; ++p)
#pragma unroll
        for (int ii = 0; ii < 4; ++ii) {
            int il = p * 64 + ti * 4 + ii;
            float rr = r2s[il];
            float* crow = C + ((size_t)b * NREF + i0 + il) * NPTS + j0;
#pragma unroll
            for (int q = 0; q < 2; ++q) {
                float4 av = acc[p][q][ii];
                float4 o;
                o.x = sqrtf(fmaxf(rr + x2v[q][0] - 2.f * av.x, 0.f)) * C2SCALE;
                o.y = sqrtf(fmaxf(rr + x2v[q][1] - 2.f * av.y, 0.f)) * C2SCALE;
                o.z = sqrtf(fmaxf(rr + x2v[q][2] - 2.f * av.z, 0.f)) * C2SCALE;
                o.w = sqrtf(fmaxf(rr + x2v[q][3] - 2.f * av.w, 0.f)) * C2SCALE;
                *(float4*)(crow + q * 64 + tj * 4) = o;
            }
        }
}

// ---------- fused u+column-partial (r11 structure, base-2 domain) ----------
// Block = (b, 16-row output chunk) processed as 4 sequential 4-row sub-chunks.
// a[4]=16 VGPR tile + online (pm,ps) column merge -> ~58 peak ->
// (512,4) 64-cap, 4 blocks/CU = 32 waves. Grid 1024 = 1 residency round.
__global__ __launch_bounds__(512, 4) void uv_kernel(const float* __restrict__ C,
                                                    const float* __restrict__ v,
                                                    float* __restrict__ u,
                                                    float* __restrict__ Pl,
                                                    float log_wx) {
    __shared__ float smx[RCH][8];
    __shared__ float sms[RCH][8];
    int b    = blockIdx.x >> 4;
    int co   = blockIdx.x & 15;          // 16-row output chunk
    int t    = threadIdx.x;
    int lane = t & 63;
    int w    = t >> 6;

    float4 vj = *(const float4*)(v + (size_t)b * NPTS + 4 * t);
    float4 pm = make_float4(-INFINITY, -INFINITY, -INFINITY, -INFINITY);
    float4 ps = make_float4(0.f, 0.f, 0.f, 0.f);

    for (int cc = 0; cc < NSUB; ++cc) {
        int r0 = co * (RCH * NSUB) + cc * RCH;
        const float* Cb = C + (size_t)(b * NREF + r0) * NPTS;

        float4 a[RCH];
#pragma unroll
        for (int i = 0; i < RCH; ++i)
            a[i] = *(const float4*)(Cb + (size_t)i * NPTS + 4 * t);

        float m[RCH], su[RCH];
#pragma unroll
        for (int i = 0; i < RCH; ++i) {
            a[i].x = vj.x - a[i].x; a[i].y = vj.y - a[i].y;
            a[i].z = vj.z - a[i].z; a[i].w = vj.w - a[i].w;
            m[i] = fmaxf(fmaxf(a[i].x, a[i].y), fmaxf(a[i].z, a[i].w));
        }
#pragma unroll
        for (int i = 0; i < RCH; ++i)
#pragma unroll
            for (int off = 1; off < 64; off <<= 1)
                m[i] = fmaxf(m[i], __shfl_xor(m[i], off));
        if (lane == 0) {
#pragma unroll
            for (int i = 0; i < RCH; ++i) smx[i][w] = m[i];
        }
        __syncthreads();
#pragma unroll
        for (int i = 0; i < RCH; ++i) {
            float mm = smx[i][0];
#pragma unroll
            for (int q = 1; q < 8; ++q) mm = fmaxf(mm, smx[i][q]);
            m[i] = mm;
        }
#pragma unroll
        for (int i = 0; i < RCH; ++i)
            su[i] = fexp2(a[i].x - m[i]) + fexp2(a[i].y - m[i])
                  + fexp2(a[i].z - m[i]) + fexp2(a[i].w - m[i]);
#pragma unroll
        for (int i = 0; i < RCH; ++i)
#pragma unroll
            for (int off = 1; off < 64; off <<= 1)
                su[i] += __shfl_xor(su[i], off);
        if (lane == 0) {
#pragma unroll
            for (int i = 0; i < RCH; ++i) sms[i][w] = su[i];
        }
        __syncthreads();
#pragma unroll
        for (int i = 0; i < RCH; ++i) {
            float s = ((sms[i][0] + sms[i][1]) + (sms[i][2] + sms[i][3]))
                    + ((sms[i][4] + sms[i][5]) + (sms[i][6] + sms[i][7]));
            su[i] = log_wx - (m[i] + flog2(s));     // su := u2_new for row r0+i
        }
#pragma unroll
        for (int i = 0; i < RCH; ++i)
            if (t == i) u[b * NREF + r0 + i] = su[i];

        // fold u into the tile in place: a := (v2 - C2) + u2
#pragma unroll
        for (int i = 0; i < RCH; ++i) {
            a[i].x += su[i]; a[i].y += su[i];
            a[i].z += su[i]; a[i].w += su[i];
        }

        // online column-LSE merge over this sub-chunk (per-column max is
        // essential: row-level shifts underflow entire columns -- C2 spread
        // ~1e4 logit units >> fp32 exp range)
#define CMERGE(Q)                                                            \
        {                                                                    \
            float mq = a[0].Q;                                               \
            _Pragma("unroll")                                                \
            for (int i_ = 1; i_ < RCH; ++i_)                                 \
                mq = fmaxf(mq, a[i_].Q);                                     \
            float nm = fmaxf(pm.Q, mq);                                      \
            float sq_ = ps.Q * fexp2(pm.Q - nm);                             \
            _Pragma("unroll")                                                \
            for (int i_ = 0; i_ < RCH; ++i_)                                 \
                sq_ += fexp2(a[i_].Q - nm);                                  \
            pm.Q = nm; ps.Q = sq_;                                           \
        }
        CMERGE(x) CMERGE(y) CMERGE(z) CMERGE(w)
#undef CMERGE
    }

    float4 pl;
    pl.x = (pm.x - vj.x) + flog2(ps.x);
    pl.y = (pm.y - vj.y) + flog2(ps.y);
    pl.z = (pm.z - vj.z) + flog2(ps.z);
    pl.w = (pm.w - vj.w) + flog2(ps.w);
    *(float4*)(Pl + (size_t)(b * NCHUNK + co) * NPTS + 4 * t) = pl;
}

// ---------- merge 16 chunk logits per column -> v ----------
__global__ __launch_bounds__(256) void vmerge_kernel(const float* __restrict__ Pl,
                                                     float* __restrict__ v,
                                                     float log_wy) {
    int b = blockIdx.x >> 3;
    int j = ((blockIdx.x & 7) << 8) + threadIdx.x;
    const float* p = Pl + (size_t)b * NCHUNK * NPTS + j;
    float l[NCHUNK];
#pragma unroll
    for (int c = 0; c < NCHUNK; ++c) l[c] = p[(size_t)c * NPTS];
    float m = l[0];
#pragma unroll
    for (int c = 1; c < NCHUNK; ++c) m = fmaxf(m, l[c]);
    float s = 0.f;
#pragma unroll
    for (int c = 0; c < NCHUNK; ++c) s += fexp2(l[c] - m);
    v[(size_t)b * NPTS + j] = log_wy - (m + flog2(s));
}

// ---------- epilogue Path A phase 1: j-split 8, 16-col inner tile ----------
// JT=16: 88 VGPR measured (r9), no spill (WRITE=66MB logical). Swizzle: 4
// quads/row, store q^((r>>3)&3), read q^(g&3). w = 2^(u2+v2-C2).
__global__ __launch_bounds__(512, 2) void out_partialA(const float* __restrict__ C,
                                                       const float* __restrict__ X,
                                                       const float* __restrict__ u,
                                                       const float* __restrict__ v,
                                                       float* __restrict__ Np,
                                                       float* __restrict__ denp) {
    __shared__ float wts[NREF * 16];    // [r][4 float4, swizzled]  16 KB
    __shared__ float xt[16 * DIM];      // [jj][d]                   8 KB
    int b  = blockIdx.x >> 3;
    int jc = blockIdx.x & 7;
    int j0 = jc * 256;
    int t  = threadIdx.x;
    int s  = t & 15;                    // d-slot
    int g  = t >> 4;                    // row group: rows g*8 .. g*8+7

    const float* Cb = C + (size_t)b * NREF * NPTS + j0;
    const float* ub = u + b * NREF;
    const float* vb = v + (size_t)b * NPTS + j0;

    float4 a0[8], a1[8];
    float ws[8];
#pragma unroll
    for (int r = 0; r < 8; ++r) {
        a0[r] = make_float4(0.f, 0.f, 0.f, 0.f);
        a1[r] = make_float4(0.f, 0.f, 0.f, 0.f);
        ws[r] = 0.f;
    }

    for (int jt = 0; jt < 256; jt += 16) {
        // stage wt: 256 rows x 16 cols = 1024 float4, 2 per thread
#pragma unroll
        for (int k = 0; k < 2; ++k) {
            int fidx = t + 512 * k;
            int r = fidx >> 2, q = fidx & 3;
            float4 cv = *(const float4*)(Cb + (size_t)r * NPTS + jt + 4 * q);
            float4 vv = *(const float4*)(vb + jt + 4 * q);
            float uu = ub[r];
            float4 wv;
            wv.x = fexp2(uu + vv.x - cv.x);
            wv.y = fexp2(uu + vv.y - cv.y);
            wv.z = fexp2(uu + vv.z - cv.z);
            wv.w = fexp2(uu + vv.w - cv.w);
            int sw = q ^ ((r >> 3) & 3);
            *(float4*)&wts[r * 16 + sw * 4] = wv;
        }
        // stage X-tile: 16 rows x 128 d = 512 float4, 1 per thread (contiguous 8KB)
        const float4* Xb4 = (const float4*)(X + ((size_t)b * NPTS + j0 + jt) * DIM);
        ((float4*)xt)[t] = Xb4[t];
        __syncthreads();

        const float4* xt4 = (const float4*)xt;
#pragma unroll 2
        for (int jp = 0; jp < 8; ++jp) {        // jj = 2*jp, 2*jp+1
            int j1 = 2 * jp;
            float4 xa0 = xt4[j1 * 32 + s];
            float4 xa1 = xt4[j1 * 32 + 16 + s];
            float4 xb0 = xt4[(j1 + 1) * 32 + s];
            float4 xb1 = xt4[(j1 + 1) * 32 + 16 + s];
            int q   = jp >> 1;
            int h   = jp & 1;
            int swb = (q ^ (g & 3)) * 4 + 2 * h;   // float offset within row's 16
#pragma unroll
            for (int rr = 0; rr < 8; ++rr) {
                int r = g * 8 + rr;
                float2 w2 = *(const float2*)&wts[r * 16 + swb];
                a0[rr].x = fmaf(w2.x, xa0.x, a0[rr].x);
                a0[rr].y = fmaf(w2.x, xa0.y, a0[rr].y);
                a0[rr].z = fmaf(w2.x, xa0.z, a0[rr].z);
                a0[rr].w = fmaf(w2.x, xa0.w, a0[rr].w);
                a1[rr].x = fmaf(w2.x, xa1.x, a1[rr].x);
                a1[rr].y = fmaf(w2.x, xa1.y, a1[rr].y);
                a1[rr].z = fmaf(w2.x, xa1.z, a1[rr].z);
                a1[rr].w = fmaf(w2.x, xa1.w, a1[rr].w);
                a0[rr].x = fmaf(w2.y, xb0.x, a0[rr].x);
                a0[rr].y = fmaf(w2.y, xb0.y, a0[rr].y);
                a0[rr].z = fmaf(w2.y, xb0.z, a0[rr].z);
                a0[rr].w = fmaf(w2.y, xb0.w, a0[rr].w);
                a1[rr].x = fmaf(w2.y, xb1.x, a1[rr].x);
                a1[rr].y = fmaf(w2.y, xb1.y, a1[rr].y);
                a1[rr].z = fmaf(w2.y, xb1.z, a1[rr].z);
                a1[rr].w = fmaf(w2.y, xb1.w, a1[rr].w);
                ws[rr] += w2.x + w2.y;
            }
        }
        __syncthreads();
    }

    // plain coalesced stores of this block's partials (disjoint (b,jc) planes)
    float* npb = Np + ((size_t)jc * BATCH * NREF + (size_t)b * NREF) * DIM;
#pragma unroll
    for (int rr = 0; rr < 8; ++rr) {
        int r = g * 8 + rr;
        float4* nrow = (float4*)(npb + (size_t)r * DIM);
        nrow[s]      = a0[rr];
        nrow[16 + s] = a1[rr];
        if (s == 0) denp[(size_t)jc * BATCH * NREF + b * NREF + r] = ws[rr];
    }
}

// ---------- epilogue Path A phase 2: deterministic 8-way combine ----------
__global__ __launch_bounds__(256) void out_finishA(const float* __restrict__ Np,
                                                   const float* __restrict__ denp,
                                                   const float* __restrict__ ref,
                                                   float* __restrict__ out) {
    const int NPL  = BATCH * NREF * DIM / 4;        // float4 per plane
    const int DENP = BATCH * NREF;
    int fidx = blockIdx.x * 256 + threadIdx.x;      // float4 index, 524288 total
    int bi   = fidx >> 5;                           // b*256 + i
    float4 n4 = make_float4(0.f, 0.f, 0.f, 0.f);
    float dn = 0.f;
    const float4* np4 = (const float4*)Np;
#pragma unroll
    for (int jc = 0; jc < 8; ++jc) {                // fixed ascending order
        float4 p = np4[(size_t)jc * NPL + fidx];
        n4.x += p.x; n4.y += p.y; n4.z += p.z; n4.w += p.w;
        dn += denp[(size_t)jc * DENP + bi];
    }
    float inv = 1.0f / (dn + 1e-8f);
    int i = bi & 255;                               // row within batch
    int q = fidx & 31;                              // d-quad
    float4 rf = ((const float4*)ref)[i * 32 + q];
    float4 o;
    o.x = n4.x * inv - rf.x;
    o.y = n4.y * inv - rf.y;
    o.z = n4.z * inv - rf.z;
    o.w = n4.w * inv - rf.w;
    ((float4*)out)[fidx] = o;
}

// ---------- epilogue Path B (fallback, proven round-3): i-split 32-row blocks ----------
__global__ __launch_bounds__(256) void out_kernelB(const float* __restrict__ C,
                                                   const float* __restrict__ X,
                                                   const float* __restrict__ ref,
                                                   const float* __restrict__ u,
                                                   const float* __restrict__ v,
                                                   float* __restrict__ out) {
    __shared__ float wt[32 * 32];       // [row_local][jj]  4 KB
    __shared__ float xt[32 * DIM];      // [jj][d]         16 KB
    int b  = blockIdx.x >> 3;
    int it = blockIdx.x & 7;
    int i0 = it * 32;
    int t  = threadIdx.x;
    int s  = t & 31;                    // d-slot (float4 at d = 4s)
    int g  = t >> 5;                    // rows i0 + g*4 .. +3

    const float* Cb = C + ((size_t)b * NREF + i0) * NPTS;
    const float* vb = v + (size_t)b * NPTS;
    const float* ub = u + (size_t)b * NREF + i0;

    float4 acc[4];
    float wsum[4];
#pragma unroll
    for (int r = 0; r < 4; ++r) { acc[r] = make_float4(0.f, 0.f, 0.f, 0.f); wsum[r] = 0.f; }

    for (int j0 = 0; j0 < NPTS; j0 += 32) {
#pragma unroll
        for (int k = 0; k < 4; ++k) {
            int widx = t + 256 * k;
            int r    = widx >> 5;
            int jj   = widx & 31;
            wt[widx] = fexp2(ub[r] + vb[j0 + jj] - Cb[(size_t)r * NPTS + j0 + jj]);
        }
        const float4* Xb4 = (const float4*)(X + ((size_t)b * NPTS + j0) * DIM);
#pragma unroll
        for (int k = 0; k < 4; ++k) {
            int idx = t + 256 * k;
            ((float4*)xt)[idx] = Xb4[idx];
        }
        __syncthreads();

        const float4* xt4 = (const float4*)xt;
#pragma unroll 2
        for (int jj = 0; jj < 32; jj += 4) {
            float4 xv0 = xt4[(jj + 0) * 32 + s];
            float4 xv1 = xt4[(jj + 1) * 32 + s];
            float4 xv2 = xt4[(jj + 2) * 32 + s];
            float4 xv3 = xt4[(jj + 3) * 32 + s];
#pragma unroll
            for (int r = 0; r < 4; ++r) {
                float4 w4 = *(const float4*)&wt[(g * 4 + r) * 32 + jj];
                acc[r].x = fmaf(w4.x, xv0.x, acc[r].x); acc[r].y = fmaf(w4.x, xv0.y, acc[r].y);
                acc[r].z = fmaf(w4.x, xv0.z, acc[r].z); acc[r].w = fmaf(w4.x, xv0.w, acc[r].w);
                acc[r].x = fmaf(w4.y, xv1.x, acc[r].x); acc[r].y = fmaf(w4.y, xv1.y, acc[r].y);
                acc[r].z = fmaf(w4.y, xv1.z, acc[r].z); acc[r].w = fmaf(w4.y, xv1.w, acc[r].w);
                acc[r].x = fmaf(w4.z, xv2.x, acc[r].x); acc[r].y = fmaf(w4.z, xv2.y, acc[r].y);
                acc[r].z = fmaf(w4.z, xv2.z, acc[r].z); acc[r].w = fmaf(w4.z, xv2.w, acc[r].w);
                acc[r].x = fmaf(w4.w, xv3.x, acc[r].x); acc[r].y = fmaf(w4.w, xv3.y, acc[r].y);
                acc[r].z = fmaf(w4.w, xv3.z, acc[r].z); acc[r].w = fmaf(w4.w, xv3.w, acc[r].w);
                wsum[r] += (w4.x + w4.y) + (w4.z + w4.w);
            }
        }
        __syncthreads();
    }

#pragma unroll
    for (int r = 0; r < 4; ++r) {
        int i = i0 + g * 4 + r;
        float dn = wsum[r] + 1e-8f;
        float inv = 1.0f / dn;
        float4 rf = ((const float4*)(ref + (size_t)i * DIM))[s];
        float4 o;
        o.x = acc[r].x * inv - rf.x;
        o.y = acc[r].y * inv - rf.y;
        o.z = acc[r].z * inv - rf.z;
        o.w = acc[r].w * inv - rf.w;
        ((float4*)(out + ((size_t)b * NREF + i) * DIM))[s] = o;
    }
}

extern "C" void kernel_launch(void* const* d_in, const int* in_sizes, int n_in,
                              void* d_out, int out_size, void* d_ws, size_t ws_size,
                              hipStream_t stream) {
    const float* X   = (const float*)d_in[0];
    const float* ref = (const float*)d_in[1];
    float* out = (float*)d_out;

    char* ws = (char*)d_ws;
    size_t o = 0;
    float* C = (float*)(ws + o); o += (size_t)BATCH * NREF * NPTS * sizeof(float);
    float* u = (float*)(ws + o); o += (size_t)BATCH * NREF * sizeof(float);
    float* v = (float*)(ws + o); o += (size_t)BATCH * NPTS * sizeof(float);
    // Pl (loop partials, 8.4 MB) is dead after the loop; Np (67.1 MB) aliases it.
    float* Pl = (float*)(ws + o);
    float* Np = (float*)(ws + o);
    size_t oA = o + (size_t)8 * BATCH * NREF * DIM * sizeof(float);
    float* denp = (float*)(ws + oA);
    oA += (size_t)8 * BATCH * NREF * sizeof(float);
    bool bigws = (ws_size >= oA);       // Path A needs ~202.4 MB total

    // base-2 logit constants: lw2 = ln(w + 1e-8) * log2(e)
    const float log_wx = (float)(log(1.0 / (double)NREF + 1e-8) * 1.4426950408889634);
    const float log_wy = (float)(log(1.0 / (double)NPTS + 1e-8) * 1.4426950408889634);

    hipMemsetAsync(v, 0, (size_t)BATCH * NPTS * sizeof(float), stream);

    cgemm_kernel<<<BATCH * 32, 256, 0, stream>>>(X, ref, C);

    for (int t = 0; t < ITERS; ++t) {
        uv_kernel<<<BATCH * NCHUNK, 512, 0, stream>>>(C, v, u, Pl, log_wx);
        vmerge_kernel<<<BATCH * NPTS / 256, 256, 0, stream>>>(Pl, v, log_wy);
    }

    if (bigws) {
        out_partialA<<<BATCH * 8, 512, 0, stream>>>(C, X, u, v, Np, denp);
        out_finishA<<<BATCH * NREF * DIM / 1024, 256, 0, stream>>>(Np, denp, ref, out);
    } else {
        out_kernelB<<<BATCH * 8, 256, 0, stream>>>(C, X, ref, u, v, out);
    }
}